// Round 1
// baseline (1903.162 us; speedup 1.0000x reference)
//
#include <hip/hip_runtime.h>
#include <hip/hip_bf16.h>

typedef __attribute__((ext_vector_type(8))) short short8;
typedef __attribute__((ext_vector_type(4))) float f32x4;

__device__ __forceinline__ float b2f(unsigned short u) {
    union { unsigned int i; float f; } v; v.i = ((unsigned int)u) << 16; return v.f;
}
__device__ __forceinline__ unsigned short f2b(float f) {
    union { float f; unsigned int i; } v; v.f = f;
    return (unsigned short)((v.i + 0x7FFFu + ((v.i >> 16) & 1u)) >> 16);
}
__device__ __forceinline__ float sigf(float x) { return 1.0f / (1.0f + __expf(-x)); }

// ---------------------------------------------------------------------------
// Prep: permute+convert token-LSTM weights to bf16 MFMA B-fragment order,
// fold biases, convert attW to fragment order.
// Wfrag layout: block b = ((dir*16+ng)*16+kk)*4+gt ; within block: lane(64) x 8 bf16
//   element = W_dir[row = gt*256 + ng*16 + (lane&15)][k = kk*32 + (lane>>4)*8 + j]
//   where k<256 -> Wih, k>=256 -> Whh (concatenated [x|h] input)
// ---------------------------------------------------------------------------
__global__ void k_prep(const float* __restrict__ Wih_f, const float* __restrict__ Whh_f,
                       const float* __restrict__ bih_f, const float* __restrict__ bhh_f,
                       const float* __restrict__ Wih_b, const float* __restrict__ Whh_b,
                       const float* __restrict__ bih_b, const float* __restrict__ bhh_b,
                       const float* __restrict__ attW,
                       short* __restrict__ Wfrag, float* __restrict__ biasp,
                       short* __restrict__ attWfrag)
{
    int idx = blockIdx.x * blockDim.x + threadIdx.x;
    if (idx < 2 * 1024 * 512) {
        int j = idx & 7, lane = (idx >> 3) & 63, b = idx >> 9;
        int gt = b & 3, kk = (b >> 2) & 15, ng = (b >> 6) & 15, dir = b >> 10;
        int u = lane & 15;
        int k = kk * 32 + (lane >> 4) * 8 + j;
        int row = gt * 256 + ng * 16 + u;
        const float* Wih = dir ? Wih_b : Wih_f;
        const float* Whh = dir ? Whh_b : Whh_f;
        float val = (k < 256) ? Wih[row * 256 + k] : Whh[row * 256 + (k - 256)];
        Wfrag[idx] = (short)f2b(val);
    } else if (idx < 2 * 1024 * 512 + 2048) {
        int i = idx - 2 * 1024 * 512;
        int dir = i >> 10, col = i & 1023;
        int ng = col >> 6, rem = col & 63, gt = rem >> 4, u = rem & 15;
        int row = gt * 256 + ng * 16 + u;
        biasp[i] = dir ? (bih_b[row] + bhh_b[row]) : (bih_f[row] + bhh_f[row]);
    } else if (idx < 2 * 1024 * 512 + 2048 + 32768) {
        int o = idx - (2 * 1024 * 512 + 2048);
        int j = o & 7, lane = (o >> 3) & 63, b = o >> 9;
        int kk = b & 7, nt = b >> 3;
        int fa = nt * 16 + (lane & 15);
        int k = kk * 32 + (lane >> 4) * 8 + j;
        attWfrag[o] = (short)f2b(attW[fa * 256 + k]);
    }
}

// ---------------------------------------------------------------------------
// Token BiLSTM, one timestep, both directions.
// 256 blocks x 256 thr: bid -> dir(1b) | ng(4b, 16-unit gate group) | mg(3b, 64-sent block)
// Per block: gates for 16 hidden units x 64 sentences.
// A = [x_t | h_{t-1}] (64 x 512) bf16 in LDS (XOR swizzled rows).
// Wave w (0..3): M-tile rows [w*16,w*16+16), 4 N-tiles = i,f,g,o of the 16 units.
// ---------------------------------------------------------------------------
__global__ __launch_bounds__(256) void k_tok(const int* __restrict__ tokens,
                                             const float* __restrict__ emb,
                                             const short* __restrict__ Wfrag,
                                             const float* __restrict__ biasp,
                                             unsigned short* __restrict__ enc_f,
                                             unsigned short* __restrict__ enc_b,
                                             float* __restrict__ c_f,
                                             float* __restrict__ c_b,
                                             int t)
{
    __shared__ char As[64 * 1024];  // 64 rows x 1024B (512 bf16), byte ^= ((row&7)<<4)
    int tid = threadIdx.x;
    int bid = blockIdx.x;
    int dir = bid >> 7;
    int ng = (bid >> 3) & 15;
    int mg = bid & 7;
    int s0 = mg * 64;
    int tcol = dir ? (127 - t) : t;
    unsigned short* enc = dir ? enc_b : enc_f;
    float* cbuf = dir ? c_b : c_f;
    bool first = (t == 0);

    // ---- stage A into LDS ----
    {
        int r = tid >> 2, q = tid & 3;   // row, quarter (256B)
        int sent = s0 + r;
        int st = (r & 7) << 1;           // stagger to spread LDS write banks
        if (q < 2) {
            int tok = tokens[sent * 128 + tcol];
            const float* src = emb + (size_t)tok * 256 + q * 128;
            #pragma unroll
            for (int i = 0; i < 16; ++i) {
                int ii = (i + st) & 15;
                float4 f0 = ((const float4*)src)[ii * 2];
                float4 f1 = ((const float4*)src)[ii * 2 + 1];
                short8 v;
                v[0] = (short)f2b(f0.x); v[1] = (short)f2b(f0.y);
                v[2] = (short)f2b(f0.z); v[3] = (short)f2b(f0.w);
                v[4] = (short)f2b(f1.x); v[5] = (short)f2b(f1.y);
                v[6] = (short)f2b(f1.z); v[7] = (short)f2b(f1.w);
                int byte = q * 256 + ii * 16;
                *(short8*)(As + r * 1024 + (byte ^ ((r & 7) << 4))) = v;
            }
        } else if (!first) {
            int hl = dir ? (128 - t) : (t - 1);
            const unsigned short* src = enc + ((size_t)hl * 512 + sent) * 256 + (q - 2) * 128;
            #pragma unroll
            for (int i = 0; i < 16; ++i) {
                int ii = (i + st) & 15;
                short8 v = *(const short8*)(src + ii * 8);
                int byte = 512 + (q - 2) * 256 + ii * 16;
                *(short8*)(As + r * 1024 + (byte ^ ((r & 7) << 4))) = v;
            }
        }
    }
    __syncthreads();

    int lane = tid & 63, w = tid >> 6;
    f32x4 acc0 = {0.f, 0.f, 0.f, 0.f};
    f32x4 acc1 = {0.f, 0.f, 0.f, 0.f};
    f32x4 acc2 = {0.f, 0.f, 0.f, 0.f};
    f32x4 acc3 = {0.f, 0.f, 0.f, 0.f};
    int kkmax = first ? 8 : 16;     // t==0: h==0, skip h half of K
    int row = w * 16 + (lane & 15);
    const short* wbase = Wfrag + ((size_t)((dir * 16 + ng) * 16) * 4) * 512 + lane * 8;
    for (int kk = 0; kk < kkmax; ++kk) {
        int byte = (kk * 32 + (lane >> 4) * 8) * 2;
        short8 a = *(const short8*)(As + row * 1024 + (byte ^ ((row & 7) << 4)));
        const short* wp = wbase + kk * 4 * 512;
        short8 b0 = *(const short8*)(wp);
        short8 b1 = *(const short8*)(wp + 512);
        short8 b2 = *(const short8*)(wp + 1024);
        short8 b3 = *(const short8*)(wp + 1536);
        acc0 = __builtin_amdgcn_mfma_f32_16x16x32_bf16(a, b0, acc0, 0, 0, 0);
        acc1 = __builtin_amdgcn_mfma_f32_16x16x32_bf16(a, b1, acc1, 0, 0, 0);
        acc2 = __builtin_amdgcn_mfma_f32_16x16x32_bf16(a, b2, acc2, 0, 0, 0);
        acc3 = __builtin_amdgcn_mfma_f32_16x16x32_bf16(a, b3, acc3, 0, 0, 0);
    }

    // ---- epilogue: gate nonlinearities + c/h update (all lane-local) ----
    int u = ng * 16 + (lane & 15);
    const float* bp = biasp + dir * 1024 + ng * 64 + (lane & 15);
    float bi = bp[0], bff = bp[16], bg = bp[32], bo = bp[48];
    int tl = dir ? (127 - t) : t;
    #pragma unroll
    for (int r = 0; r < 4; ++r) {
        int sent = s0 + w * 16 + (lane >> 4) * 4 + r;
        float gi = acc0[r] + bi;
        float gf = acc1[r] + bff;
        float gg = acc2[r] + bg;
        float go = acc3[r] + bo;
        float c_old = first ? 0.f : cbuf[sent * 256 + u];
        float cn = sigf(gf) * c_old + sigf(gi) * tanhf(gg);
        float h = sigf(go) * tanhf(cn);
        cbuf[sent * 256 + u] = cn;
        enc[((size_t)tl * 512 + sent) * 256 + u] = f2b(h);
    }
}

// ---------------------------------------------------------------------------
// Attention pooling, fully fused per sentence. 512 blocks x 256 thr.
// ---------------------------------------------------------------------------
__global__ __launch_bounds__(256) void k_att(const unsigned short* __restrict__ enc_f,
                                             const unsigned short* __restrict__ enc_b,
                                             const short* __restrict__ attWfrag,
                                             const float* __restrict__ attb,
                                             const float* __restrict__ ctx,
                                             unsigned short* __restrict__ sent16)
{
    __shared__ char encs[128 * 512];   // bf16 [128][256], byte ^= ((l&7)<<4)
    __shared__ float hid[128][129];
    __shared__ float sc[128][5];
    __shared__ float ctxs[4][128];
    __shared__ float attbs[128];
    int s = blockIdx.x;
    int tid = threadIdx.x;
    int lane = tid & 63, w = tid >> 6;

    if (tid < 128) {
        attbs[tid] = attb[tid];
        #pragma unroll
        for (int h = 0; h < 4; ++h) ctxs[h][tid] = ctx[h * 128 + tid];
    }
    // stage encsum = enc_f + enc_b
    {
        int r = tid >> 1, half = tid & 1;
        const unsigned short* pf_ = enc_f + ((size_t)r * 512 + s) * 256 + half * 128;
        const unsigned short* pb_ = enc_b + ((size_t)r * 512 + s) * 256 + half * 128;
        int st = (r & 7) << 1;
        #pragma unroll
        for (int i = 0; i < 16; ++i) {
            int ii = (i + st) & 15;
            short8 vf = *(const short8*)(pf_ + ii * 8);
            short8 vb = *(const short8*)(pb_ + ii * 8);
            short8 v;
            #pragma unroll
            for (int j = 0; j < 8; ++j)
                v[j] = (short)f2b(b2f((unsigned short)vf[j]) + b2f((unsigned short)vb[j]));
            int byte = half * 256 + ii * 16;
            *(short8*)(encs + r * 512 + (byte ^ ((r & 7) << 4))) = v;
        }
    }
    __syncthreads();

    // hidden = encsum @ attW^T + attb   (M=128 l, N=128 fa, K=256)
    {
        f32x4 acc[2][8];
        #pragma unroll
        for (int a = 0; a < 2; ++a)
            #pragma unroll
            for (int b = 0; b < 8; ++b) acc[a][b] = (f32x4){0.f, 0.f, 0.f, 0.f};
        int r0 = w * 32 + (lane & 15);
        int r1 = r0 + 16;
        for (int kk = 0; kk < 8; ++kk) {
            int byte = (kk * 32 + (lane >> 4) * 8) * 2;
            short8 a0 = *(const short8*)(encs + r0 * 512 + (byte ^ ((r0 & 7) << 4)));
            short8 a1 = *(const short8*)(encs + r1 * 512 + (byte ^ ((r1 & 7) << 4)));
            #pragma unroll
            for (int nt = 0; nt < 8; ++nt) {
                short8 b = *(const short8*)(attWfrag + ((size_t)(nt * 8 + kk)) * 512 + lane * 8);
                acc[0][nt] = __builtin_amdgcn_mfma_f32_16x16x32_bf16(a0, b, acc[0][nt], 0, 0, 0);
                acc[1][nt] = __builtin_amdgcn_mfma_f32_16x16x32_bf16(a1, b, acc[1][nt], 0, 0, 0);
            }
        }
        #pragma unroll
        for (int mt = 0; mt < 2; ++mt)
            #pragma unroll
            for (int nt = 0; nt < 8; ++nt) {
                int fa = nt * 16 + (lane & 15);
                float ab = attbs[fa];
                #pragma unroll
                for (int r = 0; r < 4; ++r) {
                    int l = w * 32 + mt * 16 + (lane >> 4) * 4 + r;
                    hid[l][fa] = acc[mt][nt][r] + ab;
                }
            }
    }
    __syncthreads();

    // scores = hidden @ ctx^T  (128 l x 4 hop)
    {
        int l = tid >> 1;
        int hb = (tid & 1) * 2;
        float d0 = 0.f, d1 = 0.f;
        for (int k = 0; k < 128; ++k) {
            float hv = hid[l][k];
            d0 += hv * ctxs[hb][k];
            d1 += hv * ctxs[hb + 1][k];
        }
        sc[l][hb] = d0;
        sc[l][hb + 1] = d1;
    }
    __syncthreads();

    // softmax over l per hop (wave w handles hop w)
    {
        float v0 = sc[lane][w];
        float v1 = sc[64 + lane][w];
        float m = fmaxf(v0, v1);
        for (int off = 32; off; off >>= 1) m = fmaxf(m, __shfl_xor(m, off));
        float e0 = __expf(v0 - m), e1 = __expf(v1 - m);
        float sm = e0 + e1;
        for (int off = 32; off; off >>= 1) sm += __shfl_xor(sm, off);
        float inv = 1.f / sm;
        sc[lane][w] = e0 * inv;
        sc[64 + lane][w] = e1 * inv;
    }
    __syncthreads();

    // sent[d][h] = sum_l encsum[l][d] * attn[l][h]; store (d*4+h) bf16
    {
        int d = tid;
        float a0 = 0.f, a1 = 0.f, a2 = 0.f, a3 = 0.f;
        int byte = d * 2;
        for (int l = 0; l < 128; ++l) {
            float e = b2f(*(const unsigned short*)(encs + l * 512 + (byte ^ ((l & 7) << 4))));
            a0 += e * sc[l][0]; a1 += e * sc[l][1]; a2 += e * sc[l][2]; a3 += e * sc[l][3];
        }
        unsigned short* o = sent16 + (size_t)s * 1024 + d * 4;
        o[0] = f2b(a0); o[1] = f2b(a1); o[2] = f2b(a2); o[3] = f2b(a3);
    }
}

// ---------------------------------------------------------------------------
// xg[dir][s][j] = sum_k sent[s][k] * sWih_dir[j][k]   (the non-recurrent part
// of the sentence LSTM). 16384 threads, one dot of 1024 each.
// ---------------------------------------------------------------------------
__global__ void k_xg(const unsigned short* __restrict__ sent16,
                     const float* __restrict__ sWih_f, const float* __restrict__ sWih_b,
                     float* __restrict__ xg)
{
    int idx = blockIdx.x * blockDim.x + threadIdx.x;  // dir(1) | s(9) | j(4)
    int dir = idx >> 13;
    int sIdx = (idx >> 4) & 511;
    int j = idx & 15;
    const float* wr = (dir ? sWih_b : sWih_f) + j * 1024;
    const unsigned short* x = sent16 + (size_t)sIdx * 1024;
    float acc = 0.f;
    for (int k = 0; k < 1024; k += 8) {
        short8 v = *(const short8*)(x + k);
        float4 w0 = *(const float4*)(wr + k);
        float4 w1 = *(const float4*)(wr + k + 4);
        acc += b2f((unsigned short)v[0]) * w0.x + b2f((unsigned short)v[1]) * w0.y
             + b2f((unsigned short)v[2]) * w0.z + b2f((unsigned short)v[3]) * w0.w
             + b2f((unsigned short)v[4]) * w1.x + b2f((unsigned short)v[5]) * w1.y
             + b2f((unsigned short)v[6]) * w1.z + b2f((unsigned short)v[7]) * w1.w;
    }
    xg[idx] = acc;
}

// ---------------------------------------------------------------------------
// Sentence BiLSTM recurrence (HOP=4). 1 block, 2 waves (wave=dir).
// Lane j<16 computes gate j; h/c (4 each) replicated in registers per lane.
// ---------------------------------------------------------------------------
__global__ void k_slstm(const float* __restrict__ xg,
                        const float* __restrict__ sWhh_f, const float* __restrict__ sbih_f,
                        const float* __restrict__ sbhh_f,
                        const float* __restrict__ sWhh_b, const float* __restrict__ sbih_b,
                        const float* __restrict__ sbhh_b,
                        float* __restrict__ hs)
{
    int tid = threadIdx.x;
    int dir = tid >> 6;
    int lane = tid & 63;
    int j = lane & 15;
    const float* Whh = dir ? sWhh_b : sWhh_f;
    float w0 = Whh[j * 4 + 0], w1 = Whh[j * 4 + 1], w2 = Whh[j * 4 + 2], w3 = Whh[j * 4 + 3];
    float sb = dir ? (sbih_b[j] + sbhh_b[j]) : (sbih_f[j] + sbhh_f[j]);
    const float* xgd = xg + dir * 8192;
    float* hd = hs + dir * 2048;
    float h0 = 0.f, h1 = 0.f, h2 = 0.f, h3 = 0.f;
    float c0 = 0.f, c1 = 0.f, c2 = 0.f, c3 = 0.f;
    int role = j >> 2;
    for (int tt = 0; tt < 512; ++tt) {
        int idx = dir ? (511 - tt) : tt;
        float g = xgd[idx * 16 + j] + sb + h0 * w0 + h1 * w1 + h2 * w2 + h3 * w3;
        float a = (role == 2) ? tanhf(g) : sigf(g);
        float i0 = __shfl(a, 0),  i1 = __shfl(a, 1),  i2 = __shfl(a, 2),  i3 = __shfl(a, 3);
        float f0 = __shfl(a, 4),  f1 = __shfl(a, 5),  f2 = __shfl(a, 6),  f3 = __shfl(a, 7);
        float g0 = __shfl(a, 8),  g1 = __shfl(a, 9),  g2 = __shfl(a, 10), g3 = __shfl(a, 11);
        float o0 = __shfl(a, 12), o1 = __shfl(a, 13), o2 = __shfl(a, 14), o3 = __shfl(a, 15);
        c0 = f0 * c0 + i0 * g0; c1 = f1 * c1 + i1 * g1;
        c2 = f2 * c2 + i2 * g2; c3 = f3 * c3 + i3 * g3;
        h0 = o0 * tanhf(c0); h1 = o1 * tanhf(c1);
        h2 = o2 * tanhf(c2); h3 = o3 * tanhf(c3);
        if (lane == 0) {
            float4 hv = {h0, h1, h2, h3};
            *(float4*)(hd + idx * 4) = hv;
        }
    }
}

// pf[s][j] = linb[j] + sum_u (hf[s][u]+hb[s][u]) * linW[j][u]
__global__ void k_pf(const float* __restrict__ hs, const float* __restrict__ linW,
                     const float* __restrict__ linb, float* __restrict__ pf)
{
    int idx = blockIdx.x * blockDim.x + threadIdx.x;  // s(9) | j(4)
    int sIdx = idx >> 4, j = idx & 15;
    float s0 = hs[sIdx * 4 + 0] + hs[2048 + sIdx * 4 + 0];
    float s1 = hs[sIdx * 4 + 1] + hs[2048 + sIdx * 4 + 1];
    float s2 = hs[sIdx * 4 + 2] + hs[2048 + sIdx * 4 + 2];
    float s3 = hs[sIdx * 4 + 3] + hs[2048 + sIdx * 4 + 3];
    pf[idx] = linb[j] + s0 * linW[j * 4 + 0] + s1 * linW[j * 4 + 1]
            + s2 * linW[j * 4 + 2] + s3 * linW[j * 4 + 3];
}

// Viterbi forward values. 1 wave; lane j holds v[j]; outputs every step.
__global__ void k_vit(const float* __restrict__ pf, const float* __restrict__ trans,
                      float* __restrict__ out)
{
    int lane = threadIdx.x & 63;
    int j = lane & 15;
    float T[16];
    #pragma unroll
    for (int r = 0; r < 16; ++r) T[r] = trans[((j + r) & 15) * 16 + j];
    float v = pf[j];
    if (lane < 16) out[j] = v;
    for (int t = 1; t < 512; ++t) {
        float m = -1e30f;
        #pragma unroll
        for (int r = 0; r < 16; ++r) {
            float vv = __shfl(v, (j + r) & 15);
            m = fmaxf(m, vv + T[r]);
        }
        v = pf[t * 16 + j] + m;
        if (lane < 16) out[t * 16 + j] = v;
    }
}

// ---------------------------------------------------------------------------
extern "C" void kernel_launch(void* const* d_in, const int* in_sizes, int n_in,
                              void* d_out, int out_size, void* d_ws, size_t ws_size,
                              hipStream_t stream) {
    (void)in_sizes; (void)n_in; (void)out_size; (void)ws_size;
    const int*   tokens = (const int*)d_in[0];
    const float* emb    = (const float*)d_in[1];
    const float* tWih_f = (const float*)d_in[2];
    const float* tWhh_f = (const float*)d_in[3];
    const float* tbih_f = (const float*)d_in[4];
    const float* tbhh_f = (const float*)d_in[5];
    const float* tWih_b = (const float*)d_in[6];
    const float* tWhh_b = (const float*)d_in[7];
    const float* tbih_b = (const float*)d_in[8];
    const float* tbhh_b = (const float*)d_in[9];
    const float* attW   = (const float*)d_in[10];
    const float* attb   = (const float*)d_in[11];
    const float* ctx    = (const float*)d_in[12];
    const float* sWih_f = (const float*)d_in[13];
    const float* sWhh_f = (const float*)d_in[14];
    const float* sbih_f = (const float*)d_in[15];
    const float* sbhh_f = (const float*)d_in[16];
    const float* sWih_b = (const float*)d_in[17];
    const float* sWhh_b = (const float*)d_in[18];
    const float* sbih_b = (const float*)d_in[19];
    const float* sbhh_b = (const float*)d_in[20];
    const float* linW   = (const float*)d_in[21];
    const float* linb   = (const float*)d_in[22];
    const float* trans  = (const float*)d_in[23];

    char* ws = (char*)d_ws;
    size_t off = 0;
    auto alloc = [&](size_t bytes) -> void* {
        void* p = ws + off;
        off += (bytes + 255) & ~(size_t)255;
        return p;
    };
    short* Wfrag            = (short*)alloc((size_t)2 * 1024 * 512 * 2);
    float* biasp            = (float*)alloc(2048 * 4);
    short* attWfrag         = (short*)alloc(32768 * 2);
    unsigned short* enc_f   = (unsigned short*)alloc((size_t)128 * 512 * 256 * 2);
    unsigned short* enc_b   = (unsigned short*)alloc((size_t)128 * 512 * 256 * 2);
    float* c_f              = (float*)alloc((size_t)512 * 256 * 4);
    float* c_b              = (float*)alloc((size_t)512 * 256 * 4);
    unsigned short* sent16  = (unsigned short*)alloc((size_t)512 * 1024 * 2);
    float* xg               = (float*)alloc(16384 * 4);
    float* hs               = (float*)alloc(4096 * 4);
    float* pf               = (float*)alloc(8192 * 4);

    int prep_total = 2 * 1024 * 512 + 2048 + 32768;
    k_prep<<<(prep_total + 255) / 256, 256, 0, stream>>>(
        tWih_f, tWhh_f, tbih_f, tbhh_f, tWih_b, tWhh_b, tbih_b, tbhh_b,
        attW, Wfrag, biasp, attWfrag);

    for (int t = 0; t < 128; ++t)
        k_tok<<<256, 256, 0, stream>>>(tokens, emb, Wfrag, biasp,
                                       enc_f, enc_b, c_f, c_b, t);

    k_att<<<512, 256, 0, stream>>>(enc_f, enc_b, attWfrag, attb, ctx, sent16);
    k_xg<<<64, 256, 0, stream>>>(sent16, sWih_f, sWih_b, xg);
    k_slstm<<<1, 128, 0, stream>>>(xg, sWhh_f, sbih_f, sbhh_f,
                                   sWhh_b, sbih_b, sbhh_b, hs);
    k_pf<<<32, 256, 0, stream>>>(hs, linW, linb, pf);
    k_vit<<<1, 64, 0, stream>>>(pf, trans, (float*)d_out);
}

// Round 2
// 1272.500 us; speedup vs baseline: 1.4956x; 1.4956x over previous
//
#include <hip/hip_runtime.h>
#include <hip/hip_bf16.h>

typedef __attribute__((ext_vector_type(8))) short short8;
typedef __attribute__((ext_vector_type(4))) float f32x4;

__device__ __forceinline__ float b2f(unsigned short u) {
    union { unsigned int i; float f; } v; v.i = ((unsigned int)u) << 16; return v.f;
}
__device__ __forceinline__ unsigned short f2b(float f) {
    union { float f; unsigned int i; } v; v.f = f;
    return (unsigned short)((v.i + 0x7FFFu + ((v.i >> 16) & 1u)) >> 16);
}
// fast sigmoid/tanh via v_exp + v_rcp (no ocml branches)
__device__ __forceinline__ float sig_f(float x) {
    return __builtin_amdgcn_rcpf(1.f + __expf(-x));
}
__device__ __forceinline__ float tanh_f(float x) {
    return 1.f - 2.f * __builtin_amdgcn_rcpf(1.f + __expf(2.f * x));
}
__device__ __forceinline__ void gll16(const void* g, void* lds) {
    __builtin_amdgcn_global_load_lds(
        (const __attribute__((address_space(1))) unsigned int*)g,
        (__attribute__((address_space(3))) unsigned int*)lds, 16, 0, 0);
}

// ---------------------------------------------------------------------------
// Prep: permute+convert token-LSTM weights to bf16 MFMA B-fragment order,
// fold biases, convert attW to fragment order.
// Wfrag layout: block b = ((dir*16+ng)*16+kk)*4+gt ; within block: lane(64) x 8 bf16
//   element = W_dir[row = gt*256 + ng*16 + (lane&15)][k = kk*32 + (lane>>4)*8 + j]
//   where k<256 -> Wih, k>=256 -> Whh (concatenated [x|h] input)
// ---------------------------------------------------------------------------
__global__ void k_prep(const float* __restrict__ Wih_f, const float* __restrict__ Whh_f,
                       const float* __restrict__ bih_f, const float* __restrict__ bhh_f,
                       const float* __restrict__ Wih_b, const float* __restrict__ Whh_b,
                       const float* __restrict__ bih_b, const float* __restrict__ bhh_b,
                       const float* __restrict__ attW,
                       short* __restrict__ Wfrag, float* __restrict__ biasp,
                       short* __restrict__ attWfrag)
{
    int idx = blockIdx.x * blockDim.x + threadIdx.x;
    if (idx < 2 * 1024 * 512) {
        int j = idx & 7, lane = (idx >> 3) & 63, b = idx >> 9;
        int gt = b & 3, kk = (b >> 2) & 15, ng = (b >> 6) & 15, dir = b >> 10;
        int u = lane & 15;
        int k = kk * 32 + (lane >> 4) * 8 + j;
        int row = gt * 256 + ng * 16 + u;
        const float* Wih = dir ? Wih_b : Wih_f;
        const float* Whh = dir ? Whh_b : Whh_f;
        float val = (k < 256) ? Wih[row * 256 + k] : Whh[row * 256 + (k - 256)];
        Wfrag[idx] = (short)f2b(val);
    } else if (idx < 2 * 1024 * 512 + 2048) {
        int i = idx - 2 * 1024 * 512;
        int dir = i >> 10, col = i & 1023;
        int ng = col >> 6, rem = col & 63, gt = rem >> 4, u = rem & 15;
        int row = gt * 256 + ng * 16 + u;
        biasp[i] = dir ? (bih_b[row] + bhh_b[row]) : (bih_f[row] + bhh_f[row]);
    } else if (idx < 2 * 1024 * 512 + 2048 + 32768) {
        int o = idx - (2 * 1024 * 512 + 2048);
        int j = o & 7, lane = (o >> 3) & 63, b = o >> 9;
        int kk = b & 7, nt = b >> 3;
        int fa = nt * 16 + (lane & 15);
        int k = kk * 32 + (lane >> 4) * 8 + j;
        attWfrag[o] = (short)f2b(attW[fa * 256 + k]);
    }
}

// convert embedding table to bf16 once (25.6MB)
__global__ void k_prep_emb(const float* __restrict__ emb, unsigned short* __restrict__ emb16)
{
    int idx = blockIdx.x * blockDim.x + threadIdx.x;
    if (idx >= 50000 * 256 / 8) return;
    const float4* s = (const float4*)(emb + (size_t)idx * 8);
    float4 a = s[0], b = s[1];
    short8 v;
    v[0] = (short)f2b(a.x); v[1] = (short)f2b(a.y);
    v[2] = (short)f2b(a.z); v[3] = (short)f2b(a.w);
    v[4] = (short)f2b(b.x); v[5] = (short)f2b(b.y);
    v[6] = (short)f2b(b.z); v[7] = (short)f2b(b.w);
    *(short8*)(emb16 + (size_t)idx * 8) = v;
}

// ---------------------------------------------------------------------------
// Token BiLSTM, one timestep, both directions.
// 256 blocks x 256 thr: bid -> dir(1b) | ng(4b) | mg(3b, 64-sent block)
// A = [x_t | h_{t-1}] (64 x 512) bf16 in LDS, logical byte b stored at
// physical b ^ ((row&7)<<4). Staged via global_load_lds with pre-swizzled
// per-lane SOURCE addresses (chunk = lane ^ (row&7)); LDS dest is linear.
// ---------------------------------------------------------------------------
__global__ __launch_bounds__(256) void k_tok(const int* __restrict__ tokens,
                                             const unsigned short* __restrict__ emb16,
                                             const short* __restrict__ Wfrag,
                                             const float* __restrict__ biasp,
                                             unsigned short* __restrict__ enc_f,
                                             unsigned short* __restrict__ enc_b,
                                             float* __restrict__ c_f,
                                             float* __restrict__ c_b,
                                             int t)
{
    __shared__ __align__(16) char As[64 * 1024];
    int tid = threadIdx.x;
    int bid = blockIdx.x;
    int dir = bid >> 7;
    int ng = (bid >> 3) & 15;
    int mg = bid & 7;
    int s0 = mg * 64;
    int tcol = dir ? (127 - t) : t;
    unsigned short* enc = dir ? enc_b : enc_f;
    float* cbuf = dir ? c_b : c_f;
    bool first = (t == 0);

    int lane = tid & 63, w = tid >> 6;

    // ---- stage A tile: wave w stages rows w*16 .. w*16+15 ----
    {
        int sent_l = s0 + w * 16 + (lane & 15);
        int tokv = tokens[sent_l * 128 + tcol];
        int hl = first ? 0 : (dir ? (128 - t) : (t - 1));
        #pragma unroll
        for (int i = 0; i < 16; ++i) {
            int r = w * 16 + i;
            int tok_i = __shfl(tokv, i);
            int sent_i = s0 + r;
            int chunk = lane ^ (i & 7);   // pre-swizzled source chunk
            const void* srcx = emb16 + (size_t)tok_i * 256 + chunk * 8;
            const void* srch = enc + ((size_t)hl * 512 + sent_i) * 256 + (chunk - 32) * 8;
            const void* src = (chunk < 32) ? srcx : srch;
            gll16(src, As + r * 1024);    // lane l -> physical byte l*16
        }
    }
    __syncthreads();

    f32x4 acc0 = {0.f, 0.f, 0.f, 0.f};
    f32x4 acc1 = {0.f, 0.f, 0.f, 0.f};
    f32x4 acc2 = {0.f, 0.f, 0.f, 0.f};
    f32x4 acc3 = {0.f, 0.f, 0.f, 0.f};
    int kkmax = first ? 8 : 16;     // t==0: h==0, skip h half of K
    int row = w * 16 + (lane & 15);
    const short* wbase = Wfrag + ((size_t)((dir * 16 + ng) * 16) * 4) * 512 + lane * 8;
    #pragma unroll 4
    for (int kk = 0; kk < kkmax; ++kk) {
        int byte = (kk * 32 + (lane >> 4) * 8) * 2;
        short8 a = *(const short8*)(As + row * 1024 + (byte ^ ((row & 7) << 4)));
        const short* wp = wbase + kk * 4 * 512;
        short8 b0 = *(const short8*)(wp);
        short8 b1 = *(const short8*)(wp + 512);
        short8 b2 = *(const short8*)(wp + 1024);
        short8 b3 = *(const short8*)(wp + 1536);
        acc0 = __builtin_amdgcn_mfma_f32_16x16x32_bf16(a, b0, acc0, 0, 0, 0);
        acc1 = __builtin_amdgcn_mfma_f32_16x16x32_bf16(a, b1, acc1, 0, 0, 0);
        acc2 = __builtin_amdgcn_mfma_f32_16x16x32_bf16(a, b2, acc2, 0, 0, 0);
        acc3 = __builtin_amdgcn_mfma_f32_16x16x32_bf16(a, b3, acc3, 0, 0, 0);
    }

    // ---- epilogue: gate nonlinearities + c/h update (lane-local) ----
    int u = ng * 16 + (lane & 15);
    const float* bp = biasp + dir * 1024 + ng * 64 + (lane & 15);
    float bi = bp[0], bff = bp[16], bg = bp[32], bo = bp[48];
    int tl = dir ? (127 - t) : t;
    #pragma unroll
    for (int r = 0; r < 4; ++r) {
        int sent = s0 + w * 16 + (lane >> 4) * 4 + r;
        float gi = acc0[r] + bi;
        float gf = acc1[r] + bff;
        float gg = acc2[r] + bg;
        float go = acc3[r] + bo;
        float c_old = first ? 0.f : cbuf[sent * 256 + u];
        float cn = sig_f(gf) * c_old + sig_f(gi) * tanh_f(gg);
        float h = sig_f(go) * tanh_f(cn);
        cbuf[sent * 256 + u] = cn;
        enc[((size_t)tl * 512 + sent) * 256 + u] = f2b(h);
    }
}

// ---------------------------------------------------------------------------
// Attention pooling, fully fused per sentence, + sentence-LSTM input
// projection xg (fused; sent row never leaves the block). 512 blocks x 256.
// xg layout (permuted for k_slstm): xg[dir*8192 + s*16 + unit*4 + gate]
// ---------------------------------------------------------------------------
__global__ __launch_bounds__(256) void k_att(const unsigned short* __restrict__ enc_f,
                                             const unsigned short* __restrict__ enc_b,
                                             const short* __restrict__ attWfrag,
                                             const float* __restrict__ attb,
                                             const float* __restrict__ ctx,
                                             const float* __restrict__ sWih_f,
                                             const float* __restrict__ sWih_b,
                                             float* __restrict__ xg)
{
    __shared__ char encs[128 * 512];   // bf16 [128][256], byte ^= ((l&7)<<4)
    __shared__ float hid[128][129];
    __shared__ float sc[128][5];
    __shared__ float ctxs[4][128];
    __shared__ float attbs[128];
    __shared__ float sentrow[1024];    // sent[d][h] at d*4+h
    int s = blockIdx.x;
    int tid = threadIdx.x;
    int lane = tid & 63, w = tid >> 6;

    if (tid < 128) {
        attbs[tid] = attb[tid];
        #pragma unroll
        for (int h = 0; h < 4; ++h) ctxs[h][tid] = ctx[h * 128 + tid];
    }
    // stage encsum = enc_f + enc_b
    {
        int r = tid >> 1, half = tid & 1;
        const unsigned short* pf_ = enc_f + ((size_t)r * 512 + s) * 256 + half * 128;
        const unsigned short* pb_ = enc_b + ((size_t)r * 512 + s) * 256 + half * 128;
        int st = (r & 7) << 1;
        #pragma unroll
        for (int i = 0; i < 16; ++i) {
            int ii = (i + st) & 15;
            short8 vf = *(const short8*)(pf_ + ii * 8);
            short8 vb = *(const short8*)(pb_ + ii * 8);
            short8 v;
            #pragma unroll
            for (int j = 0; j < 8; ++j)
                v[j] = (short)f2b(b2f((unsigned short)vf[j]) + b2f((unsigned short)vb[j]));
            int byte = half * 256 + ii * 16;
            *(short8*)(encs + r * 512 + (byte ^ ((r & 7) << 4))) = v;
        }
    }
    __syncthreads();

    // hidden = encsum @ attW^T + attb   (M=128 l, N=128 fa, K=256)
    {
        f32x4 acc[2][8];
        #pragma unroll
        for (int a = 0; a < 2; ++a)
            #pragma unroll
            for (int b = 0; b < 8; ++b) acc[a][b] = (f32x4){0.f, 0.f, 0.f, 0.f};
        int r0 = w * 32 + (lane & 15);
        int r1 = r0 + 16;
        for (int kk = 0; kk < 8; ++kk) {
            int byte = (kk * 32 + (lane >> 4) * 8) * 2;
            short8 a0 = *(const short8*)(encs + r0 * 512 + (byte ^ ((r0 & 7) << 4)));
            short8 a1 = *(const short8*)(encs + r1 * 512 + (byte ^ ((r1 & 7) << 4)));
            #pragma unroll
            for (int nt = 0; nt < 8; ++nt) {
                short8 b = *(const short8*)(attWfrag + ((size_t)(nt * 8 + kk)) * 512 + lane * 8);
                acc[0][nt] = __builtin_amdgcn_mfma_f32_16x16x32_bf16(a0, b, acc[0][nt], 0, 0, 0);
                acc[1][nt] = __builtin_amdgcn_mfma_f32_16x16x32_bf16(a1, b, acc[1][nt], 0, 0, 0);
            }
        }
        #pragma unroll
        for (int mt = 0; mt < 2; ++mt)
            #pragma unroll
            for (int nt = 0; nt < 8; ++nt) {
                int fa = nt * 16 + (lane & 15);
                float ab = attbs[fa];
                #pragma unroll
                for (int r = 0; r < 4; ++r) {
                    int l = w * 32 + mt * 16 + (lane >> 4) * 4 + r;
                    hid[l][fa] = acc[mt][nt][r] + ab;
                }
            }
    }
    __syncthreads();

    // scores = hidden @ ctx^T  (128 l x 4 hop)
    {
        int l = tid >> 1;
        int hb = (tid & 1) * 2;
        float d0 = 0.f, d1 = 0.f;
        for (int k = 0; k < 128; ++k) {
            float hv = hid[l][k];
            d0 += hv * ctxs[hb][k];
            d1 += hv * ctxs[hb + 1][k];
        }
        sc[l][hb] = d0;
        sc[l][hb + 1] = d1;
    }
    __syncthreads();

    // softmax over l per hop (wave w handles hop w)
    {
        float v0 = sc[lane][w];
        float v1 = sc[64 + lane][w];
        float m = fmaxf(v0, v1);
        for (int off = 32; off; off >>= 1) m = fmaxf(m, __shfl_xor(m, off));
        float e0 = __expf(v0 - m), e1 = __expf(v1 - m);
        float sm = e0 + e1;
        for (int off = 32; off; off >>= 1) sm += __shfl_xor(sm, off);
        float inv = 1.f / sm;
        sc[lane][w] = e0 * inv;
        sc[64 + lane][w] = e1 * inv;
    }
    __syncthreads();

    // sent[d][h] = sum_l encsum[l][d] * attn[l][h]
    {
        int d = tid;
        float a0 = 0.f, a1 = 0.f, a2 = 0.f, a3 = 0.f;
        int byte = d * 2;
        for (int l = 0; l < 128; ++l) {
            float e = b2f(*(const unsigned short*)(encs + l * 512 + (byte ^ ((l & 7) << 4))));
            a0 += e * sc[l][0]; a1 += e * sc[l][1]; a2 += e * sc[l][2]; a3 += e * sc[l][3];
        }
        sentrow[d * 4 + 0] = a0; sentrow[d * 4 + 1] = a1;
        sentrow[d * 4 + 2] = a2; sentrow[d * 4 + 3] = a3;
    }
    __syncthreads();

    // xg[dir][s][j'] = dot(sentrow, sWih_dir[j]); 8 threads per (dir,j)
    {
        int p = tid >> 3;          // 0..31: dir(1) | j(4)
        int sub = tid & 7;
        int dirq = p >> 4, j = p & 15;
        const float* wr = (dirq ? sWih_b : sWih_f) + j * 1024 + sub * 128;
        const float* sr = sentrow + sub * 128;
        float acc = 0.f;
        #pragma unroll
        for (int k = 0; k < 128; k += 4) {
            float4 wv = *(const float4*)(wr + k);
            float4 sv = *(const float4*)(sr + k);
            acc += sv.x * wv.x + sv.y * wv.y + sv.z * wv.z + sv.w * wv.w;
        }
        acc += __shfl_xor(acc, 1);
        acc += __shfl_xor(acc, 2);
        acc += __shfl_xor(acc, 4);
        if (sub == 0)
            xg[dirq * 8192 + s * 16 + (j & 3) * 4 + (j >> 2)] = acc;
    }
}

// ---------------------------------------------------------------------------
// Sentence BiLSTM recurrence (HOP=4). 1 block, 2 waves (wave=dir).
// xg preloaded to LDS; lane u (=lane&3) owns hidden unit u (all 4 gates).
// ---------------------------------------------------------------------------
__global__ void k_slstm(const float* __restrict__ xg,
                        const float* __restrict__ sWhh_f, const float* __restrict__ sbih_f,
                        const float* __restrict__ sbhh_f,
                        const float* __restrict__ sWhh_b, const float* __restrict__ sbih_b,
                        const float* __restrict__ sbhh_b,
                        float* __restrict__ hs)
{
    __shared__ float xs[16384];   // [dir][512][16], 64KB
    int tid = threadIdx.x;        // 128
    for (int i = tid; i < 4096; i += 128)
        ((float4*)xs)[i] = ((const float4*)xg)[i];
    __syncthreads();

    int dir = tid >> 6, lane = tid & 63;
    int u = lane & 3;
    const float* Whh = dir ? sWhh_b : sWhh_f;
    const float* bih = dir ? sbih_b : sbih_f;
    const float* bhh = dir ? sbhh_b : sbhh_f;
    float4 wI = *(const float4*)(Whh + (0 + u) * 4);
    float4 wF = *(const float4*)(Whh + (4 + u) * 4);
    float4 wG = *(const float4*)(Whh + (8 + u) * 4);
    float4 wO = *(const float4*)(Whh + (12 + u) * 4);
    float bI = bih[u] + bhh[u];
    float bF = bih[4 + u] + bhh[4 + u];
    float bG = bih[8 + u] + bhh[8 + u];
    float bO = bih[12 + u] + bhh[12 + u];
    const float* xd = xs + dir * 8192;
    float* hd = hs + dir * 2048;
    float h0 = 0.f, h1 = 0.f, h2 = 0.f, h3 = 0.f, c = 0.f;

    int idx0 = dir ? 511 : 0;
    float4 xv = *(const float4*)(xd + idx0 * 16 + u * 4);
    for (int tt = 0; tt < 512; ++tt) {
        int cidx = dir ? (511 - tt) : tt;
        int nidx = dir ? (510 - tt) : (tt + 1);
        nidx = nidx < 0 ? 0 : (nidx > 511 ? 511 : nidx);
        float4 xn = *(const float4*)(xd + nidx * 16 + u * 4);
        float gI = xv.x + bI + h0 * wI.x + h1 * wI.y + h2 * wI.z + h3 * wI.w;
        float gF = xv.y + bF + h0 * wF.x + h1 * wF.y + h2 * wF.z + h3 * wF.w;
        float gG = xv.z + bG + h0 * wG.x + h1 * wG.y + h2 * wG.z + h3 * wG.w;
        float gO = xv.w + bO + h0 * wO.x + h1 * wO.y + h2 * wO.z + h3 * wO.w;
        c = sig_f(gF) * c + sig_f(gI) * tanh_f(gG);
        float hu = sig_f(gO) * tanh_f(c);
        h0 = __shfl(hu, 0); h1 = __shfl(hu, 1);
        h2 = __shfl(hu, 2); h3 = __shfl(hu, 3);
        if (lane == 0) {
            float4 hv = {h0, h1, h2, h3};
            *(float4*)(hd + cidx * 4) = hv;
        }
        xv = xn;
    }
}

// ---------------------------------------------------------------------------
// pf (linear head) + Viterbi, fused. 1 block x 256; pf lives in LDS.
// ---------------------------------------------------------------------------
__global__ void k_vitpf(const float* __restrict__ hs, const float* __restrict__ linW,
                        const float* __restrict__ linb, const float* __restrict__ trans,
                        float* __restrict__ out)
{
    __shared__ float pfs[8192];   // [512][16]
    int tid = threadIdx.x;
    for (int i = tid; i < 8192; i += 256) {
        int s = i >> 4, j = i & 15;
        float acc = linb[j];
        #pragma unroll
        for (int u = 0; u < 4; ++u)
            acc += (hs[s * 4 + u] + hs[2048 + s * 4 + u]) * linW[j * 4 + u];
        pfs[i] = acc;
    }
    __syncthreads();
    if (tid < 64) {
        int j = tid & 15;
        float T[16];
        #pragma unroll
        for (int r = 0; r < 16; ++r) T[r] = trans[((j + r) & 15) * 16 + j];
        float v = pfs[j];
        if (tid < 16) out[j] = v;
        for (int t = 1; t < 512; ++t) {
            float m = -1e30f;
            #pragma unroll
            for (int r = 0; r < 16; ++r) {
                float vv = __shfl(v, (j + r) & 15);
                m = fmaxf(m, vv + T[r]);
            }
            v = pfs[t * 16 + j] + m;
            if (tid < 16) out[t * 16 + j] = v;
        }
    }
}

// ---------------------------------------------------------------------------
extern "C" void kernel_launch(void* const* d_in, const int* in_sizes, int n_in,
                              void* d_out, int out_size, void* d_ws, size_t ws_size,
                              hipStream_t stream) {
    (void)in_sizes; (void)n_in; (void)out_size; (void)ws_size;
    const int*   tokens = (const int*)d_in[0];
    const float* emb    = (const float*)d_in[1];
    const float* tWih_f = (const float*)d_in[2];
    const float* tWhh_f = (const float*)d_in[3];
    const float* tbih_f = (const float*)d_in[4];
    const float* tbhh_f = (const float*)d_in[5];
    const float* tWih_b = (const float*)d_in[6];
    const float* tWhh_b = (const float*)d_in[7];
    const float* tbih_b = (const float*)d_in[8];
    const float* tbhh_b = (const float*)d_in[9];
    const float* attW   = (const float*)d_in[10];
    const float* attb   = (const float*)d_in[11];
    const float* ctx    = (const float*)d_in[12];
    const float* sWih_f = (const float*)d_in[13];
    const float* sWhh_f = (const float*)d_in[14];
    const float* sbih_f = (const float*)d_in[15];
    const float* sbhh_f = (const float*)d_in[16];
    const float* sWih_b = (const float*)d_in[17];
    const float* sWhh_b = (const float*)d_in[18];
    const float* sbih_b = (const float*)d_in[19];
    const float* sbhh_b = (const float*)d_in[20];
    const float* linW   = (const float*)d_in[21];
    const float* linb   = (const float*)d_in[22];
    const float* trans  = (const float*)d_in[23];

    char* ws = (char*)d_ws;
    size_t off = 0;
    auto alloc = [&](size_t bytes) -> void* {
        void* p = ws + off;
        off += (bytes + 255) & ~(size_t)255;
        return p;
    };
    short* Wfrag            = (short*)alloc((size_t)2 * 1024 * 512 * 2);
    float* biasp            = (float*)alloc(2048 * 4);
    short* attWfrag         = (short*)alloc(32768 * 2);
    unsigned short* emb16   = (unsigned short*)alloc((size_t)50000 * 256 * 2);
    unsigned short* enc_f   = (unsigned short*)alloc((size_t)128 * 512 * 256 * 2);
    unsigned short* enc_b   = (unsigned short*)alloc((size_t)128 * 512 * 256 * 2);
    float* c_f              = (float*)alloc((size_t)512 * 256 * 4);
    float* c_b              = (float*)alloc((size_t)512 * 256 * 4);
    float* xg               = (float*)alloc(16384 * 4);
    float* hs               = (float*)alloc(4096 * 4);

    int prep_total = 2 * 1024 * 512 + 2048 + 32768;
    k_prep<<<(prep_total + 255) / 256, 256, 0, stream>>>(
        tWih_f, tWhh_f, tbih_f, tbhh_f, tWih_b, tWhh_b, tbih_b, tbhh_b,
        attW, Wfrag, biasp, attWfrag);
    k_prep_emb<<<(50000 * 256 / 8 + 255) / 256, 256, 0, stream>>>(emb, emb16);

    for (int t = 0; t < 128; ++t)
        k_tok<<<256, 256, 0, stream>>>(tokens, emb16, Wfrag, biasp,
                                       enc_f, enc_b, c_f, c_b, t);

    k_att<<<512, 256, 0, stream>>>(enc_f, enc_b, attWfrag, attb, ctx,
                                   sWih_f, sWih_b, xg);
    k_slstm<<<1, 128, 0, stream>>>(xg, sWhh_f, sbih_f, sbhh_f,
                                   sWhh_b, sbih_b, sbhh_b, hs);
    k_vitpf<<<1, 256, 0, stream>>>(hs, linW, linb, trans, (float*)d_out);
}